// Round 6
// baseline (37165.277 us; speedup 1.0000x reference)
//
#include <hip/hip_runtime.h>

// ResLSTM: T=512, B=128, IN=H=1024, L=4. Launch-per-superstep (515), diagonal wavefront.
// R6: granule pipeline. Per WG (256 thr = 4 waves, BM=128 BN=16): K walked in 24
// granules of 128. B staged via global_load_lds into 4-buffer LDS rotation (B-only,
// 16 KB/granule, 64 KB total); one vmcnt(8)+barrier per granule. A-operands loaded
// to REGISTERS in a per-granule batch issued BEFORE the stage ops, so compiler
// use-waits are vmcnt(>=4) and never drain the DMA queue (R3/R5's hidden serializer).
// Each wave owns 32 rows (2 MFMA A-frags) -> B LDS reads halved vs 8-wave version.

#define TT 512
#define BB 128
#define IN_D 1024
#define HH 1024
#define LL 4
#define G3 3072
#define NSUPER (TT + LL - 1)
#define NGRAN 24
#define GBUF 16384            // B bytes per granule: 4 groups x 16 rows x 256 B
#define NBUF 4
#define SLOT (BB * HH)
#define SLOT_ALL (LL * SLOT)

typedef __attribute__((ext_vector_type(8))) __bf16 bf16x8;
typedef __attribute__((ext_vector_type(4))) __bf16 bf16x4;
typedef __attribute__((ext_vector_type(4))) float f32x4;

typedef __attribute__((address_space(3))) void lds_void;
typedef const __attribute__((address_space(1))) void gmem_void;

__device__ __forceinline__ void gload_lds16(const void* g, void* l) {
    __builtin_amdgcn_global_load_lds((gmem_void*)g, (lds_void*)l, 16, 0, 0);
}

__device__ __forceinline__ f32x4 mfma16(bf16x8 a, bf16x8 b, f32x4 c) {
    return __builtin_amdgcn_mfma_f32_16x16x32_bf16(a, b, c, 0, 0, 0);
}

__device__ __forceinline__ bf16x8 cvt8(float4 u, float4 v) {
    bf16x8 r;
    r[0] = (__bf16)u.x; r[1] = (__bf16)u.y; r[2] = (__bf16)u.z; r[3] = (__bf16)u.w;
    r[4] = (__bf16)v.x; r[5] = (__bf16)v.y; r[6] = (__bf16)v.z; r[7] = (__bf16)v.w;
    return r;
}

__device__ __forceinline__ float sigm(float v) { return 1.f / (1.f + __expf(-v)); }
__device__ __forceinline__ float tanh_fast(float v) { return 1.f - 2.f / (1.f + __expf(2.f * v)); }

// ---- fused gates weight: Wg[j][n][k], k<1024:Wii, k<2048:Wih, else:Wic ----
__global__ void k_conv_gates(const float* __restrict__ Wii,
                             const float* __restrict__ Wic,
                             const float* __restrict__ Wih,
                             __bf16* __restrict__ Wg) {
    const unsigned total = (unsigned)LL * G3 * G3;
    const unsigned stride = gridDim.x * blockDim.x * 4u;
    for (unsigned idx = (blockIdx.x * blockDim.x + threadIdx.x) * 4u; idx < total; idx += stride) {
        unsigned row = idx / G3;
        int k = (int)(idx - row * G3);
        const float* src; int ks;
        if (k < 1024)      { src = Wii; ks = k; }
        else if (k < 2048) { src = Wih; ks = k - 1024; }
        else               { src = Wic; ks = k - 2048; }
        float4 v = *reinterpret_cast<const float4*>(src + (size_t)row * 1024 + ks);
        bf16x4 o;
        o[0] = (__bf16)v.x; o[1] = (__bf16)v.y; o[2] = (__bf16)v.z; o[3] = (__bf16)v.w;
        *reinterpret_cast<bf16x4*>(Wg + idx) = o;
    }
}

__global__ void k_conv_plain(const float* __restrict__ s, __bf16* __restrict__ d, unsigned total) {
    const unsigned stride = gridDim.x * blockDim.x * 4u;
    for (unsigned idx = (blockIdx.x * blockDim.x + threadIdx.x) * 4u; idx < total; idx += stride) {
        float4 v = *reinterpret_cast<const float4*>(s + idx);
        bf16x4 o;
        o[0] = (__bf16)v.x; o[1] = (__bf16)v.y; o[2] = (__bf16)v.z; o[3] = (__bf16)v.w;
        *reinterpret_cast<bf16x4*>(d + idx) = o;
    }
}

__global__ void k_bias(const float* __restrict__ bii, const float* __restrict__ bic,
                       const float* __restrict__ bih, const float* __restrict__ bhh,
                       float* __restrict__ bsum) {
    int i = blockIdx.x * blockDim.x + threadIdx.x;
    int j = i >> 12, n = i & 4095;
    if (j >= LL) return;
    if (n < G3) bsum[j * 4096 + n] = bii[j * G3 + n] + bih[j * G3 + n] + bic[j * G3 + n];
    else        bsum[j * 4096 + n] = bhh[j * HH + (n - G3)];
}

// hidden [2L,B,H] -> parity-1 slots ("t = -1")
__global__ void k_init(const float* __restrict__ hidden,
                       float* __restrict__ cbufF, __bf16* __restrict__ hb, __bf16* __restrict__ cb) {
    const unsigned stride = gridDim.x * blockDim.x;
    for (unsigned i = blockIdx.x * blockDim.x + threadIdx.x; i < SLOT_ALL; i += stride) {
        float hv = hidden[i];
        float cv = hidden[SLOT_ALL + i];
        hb[SLOT_ALL + i] = (__bf16)hv;
        cb[SLOT_ALL + i] = (__bf16)cv;
        cbufF[SLOT_ALL + i] = cv;
    }
}

__global__ void k_final(const float* __restrict__ hfin, const float* __restrict__ cbufF,
                        float* __restrict__ out_tail) {
    const unsigned stride = gridDim.x * blockDim.x;
    for (unsigned i = blockIdx.x * blockDim.x + threadIdx.x; i < SLOT_ALL; i += stride) {
        out_tail[i] = hfin[i];
        out_tail[SLOT_ALL + i] = cbufF[SLOT_ALL + i];
    }
}

// superstep s: layer j = blockIdx.y computes t = s - j. grid (64,4) x 256 threads.
// Wave w owns rows 32w..32w+31 (2 A-frags). BN=16 cols (n0). 24 granules of K=128:
//   g 0..7  (rg0): A = layer input (x / prev-layer h), B = {Wi,Wf,Wo,Wir}
//   g 8..15 (rg1): A = h, B = {Wi,Wf,Wo,Whh}
//   g 16..23(rg2): A = c, B = {Wi,Wf,Wo,(dup)}
// B LDS layout per granule-buf: group G at G*4096, [16 rows][16 slots x 16B],
// slot XOR-swizzled by (row&7) via pre-swizzled global source (bank-conflict-free).
__global__ __launch_bounds__(256) void k_super(
    const float* __restrict__ x,
    const __bf16* __restrict__ Wg,
    const __bf16* __restrict__ Whh,
    const __bf16* __restrict__ Wir,
    const float* __restrict__ bsum,
    float* __restrict__ cbufF,
    __bf16* __restrict__ hb,
    __bf16* __restrict__ cb,
    float* __restrict__ hfin,
    float* __restrict__ dout,
    int s)
{
    const int j = blockIdx.y;
    const int t = s - j;
    if (t < 0 || t >= TT) return;

    __shared__ __align__(16) char smem[NBUF * GBUF];   // 64 KiB

    const int p = t & 1, pp = p ^ 1;
    const float*  csrcF = cbufF + (size_t)pp * SLOT_ALL + (size_t)j * SLOT;
    float*        cdstF = cbufF + (size_t)p  * SLOT_ALL + (size_t)j * SLOT;
    const __bf16* panH = hb + (size_t)pp * SLOT_ALL + (size_t)j * SLOT;
    const __bf16* panC = cb + (size_t)pp * SLOT_ALL + (size_t)j * SLOT;
    const __bf16* panO = (j == 0) ? panH                                  // unused for j==0
                                  : hb + (size_t)p * SLOT_ALL + (size_t)(j - 1) * SLOT;
    __bf16* hdstB = hb + (size_t)p * SLOT_ALL + (size_t)j * SLOT;
    __bf16* cdstB = cb + (size_t)p * SLOT_ALL + (size_t)j * SLOT;

    const int tid  = threadIdx.x;
    const int lane = tid & 63;
    const int w    = tid >> 6;        // wave 0..3
    const int lrow = lane & 15;       // frag row/col index
    const int kgrp = lane >> 4;       // k-group 0..3
    const int row4 = lane >> 4;       // stage: row-within-op
    const int slot = lane & 15;       // stage: physical 16B slot
    const int n0   = blockIdx.x * 16;

    // ---- stage source pointers (B): wave w stages gate-group w, 4 ops of 4 rows ----
    const __bf16* Wgj = Wg + (size_t)j * G3 * G3;
    const __bf16* bA[4];  // rg0 source
    const __bf16* bB[4];  // rg1/rg2 source
    #pragma unroll
    for (int o = 0; o < 4; ++o) {
        const int row = 4 * o + row4;                     // 0..15 (output col within tile)
        const int kel = (slot ^ (row & 7)) << 3;          // pre-swizzled k element offset
        if (w < 3) {
            bA[o] = Wgj + (size_t)(w * 1024 + n0 + row) * G3 + kel;
            bB[o] = bA[o];
        } else {
            bA[o] = Wir + (size_t)j * HH * IN_D + (size_t)(n0 + row) * IN_D + kel;
            bB[o] = Whh + (size_t)j * HH * HH  + (size_t)(n0 + row) * HH  + kel;
        }
    }
    char* st_dst0 = smem + w * 4096 + (lane << 4);

    auto stage = [&](int g) {
        if (g >= NGRAN) return;
        const int rg = g >> 3;
        char* dst = st_dst0 + (g & 3) * GBUF;
        const long gkw = (w < 3) ? ((long)g << 7) : ((long)(g & 7) << 7);
        #pragma unroll
        for (int o = 0; o < 4; ++o)
            gload_lds16(((rg == 0) ? bA[o] : bB[o]) + gkw, dst + o * 1024);
    };

    // ---- A row pointers (registers path) ----
    const __bf16* pH0 = panH + (size_t)(32 * w + lrow) * HH;
    const __bf16* pH1 = pH0 + (size_t)16 * HH;
    const __bf16* pC0 = panC + (size_t)(32 * w + lrow) * HH;
    const __bf16* pC1 = pC0 + (size_t)16 * HH;
    const __bf16* pO0 = panO + (size_t)(32 * w + lrow) * HH;
    const __bf16* pO1 = pO0 + (size_t)16 * HH;
    const float*  xr0 = x + (size_t)t * SLOT + (size_t)(32 * w + lrow) * IN_D;
    const float*  xr1 = xr0 + (size_t)16 * IN_D;
    const int kg8 = kgrp << 3;

    f32x4 vi[2] = {{0,0,0,0},{0,0,0,0}}, vf_[2] = {{0,0,0,0},{0,0,0,0}},
          vo[2] = {{0,0,0,0},{0,0,0,0}}, vc[2] = {{0,0,0,0},{0,0,0,0}},
          vr[2] = {{0,0,0,0},{0,0,0,0}};

    // prologue: stage granules 0..2, wait for g0 (8 = stages 1,2 outstanding)
    stage(0); stage(1); stage(2);
    asm volatile("s_waitcnt vmcnt(8)" ::: "memory");
    __builtin_amdgcn_s_barrier();

    for (int g = 0; g < NGRAN; ++g) {
        const int rg = g >> 3;
        const int kw = (g & 7) << 7;
        const char* buf = smem + (g & 3) * GBUF;
        const bool xpath = (j == 0) & (rg == 0);

        // ---- A batch for this granule (issued BEFORE stage ops) ----
        bf16x8 ab0[4], ab1[4];
        float4 xq0a[4], xq0b[4], xq1a[4], xq1b[4];
        if (xpath) {
            #pragma unroll
            for (int cc = 0; cc < 4; ++cc) {
                const int ko = kw + cc * 32 + kg8;
                xq0a[cc] = *(const float4*)(xr0 + ko);
                xq0b[cc] = *(const float4*)(xr0 + ko + 4);
                xq1a[cc] = *(const float4*)(xr1 + ko);
                xq1b[cc] = *(const float4*)(xr1 + ko + 4);
            }
        } else {
            const __bf16* r0 = (rg == 0) ? pO0 : (rg == 1) ? pH0 : pC0;
            const __bf16* r1 = (rg == 0) ? pO1 : (rg == 1) ? pH1 : pC1;
            #pragma unroll
            for (int cc = 0; cc < 4; ++cc) {
                const int ko = kw + cc * 32 + kg8;
                ab0[cc] = *(const bf16x8*)(r0 + ko);
                ab1[cc] = *(const bf16x8*)(r1 + ko);
            }
        }

        stage(g + 3);

        // ---- compute: 4 chunks of K=32 ----
        #pragma unroll
        for (int cc = 0; cc < 4; ++cc) {
            const int sw = ((cc * 4 + kgrp) ^ (lrow & 7)) << 4;
            const char* bb = buf + (lrow << 8) + sw;
            bf16x8 a0 = xpath ? cvt8(xq0a[cc], xq0b[cc]) : ab0[cc];
            bf16x8 a1 = xpath ? cvt8(xq1a[cc], xq1b[cc]) : ab1[cc];
            bf16x8 b0 = *(const bf16x8*)(bb);
            bf16x8 b1 = *(const bf16x8*)(bb + 4096);
            bf16x8 b2 = *(const bf16x8*)(bb + 8192);
            vi[0] = mfma16(a0, b0, vi[0]);  vi[1] = mfma16(a1, b0, vi[1]);
            vf_[0] = mfma16(a0, b1, vf_[0]); vf_[1] = mfma16(a1, b1, vf_[1]);
            vo[0] = mfma16(a0, b2, vo[0]);  vo[1] = mfma16(a1, b2, vo[1]);
            if (rg == 0) {
                bf16x8 b3 = *(const bf16x8*)(bb + 12288);
                vr[0] = mfma16(a0, b3, vr[0]); vr[1] = mfma16(a1, b3, vr[1]);
            } else if (rg == 1) {
                bf16x8 b3 = *(const bf16x8*)(bb + 12288);
                vc[0] = mfma16(a0, b3, vc[0]); vc[1] = mfma16(a1, b3, vc[1]);
            }
        }

        // granule g+1 guaranteed staged: allow only stages (g+2),(g+3) = 8 ops outstanding
        if (g == NGRAN - 2)     { asm volatile("s_waitcnt vmcnt(0)" ::: "memory"); }
        else if (g < NGRAN - 2) { asm volatile("s_waitcnt vmcnt(8)" ::: "memory"); }
        if (g < NGRAN - 1) __builtin_amdgcn_s_barrier();
    }

    // ---- elementwise epilogue ----
    const int col = n0 + lrow;
    const float b_i = bsum[j * 4096 + col];
    const float b_f = bsum[j * 4096 + HH + col];
    const float b_o = bsum[j * 4096 + 2 * HH + col];
    const float b_c = bsum[j * 4096 + G3 + col];

    #pragma unroll
    for (int f = 0; f < 2; ++f) {
        #pragma unroll
        for (int r = 0; r < 4; ++r) {
            const int m = 32 * w + 16 * f + kgrp * 4 + r;
            const size_t o = (size_t)m * HH + col;
            float iv = vi[f][r] + b_i;
            float fv = vf_[f][r] + b_f;
            float ov = vo[f][r] + b_o;
            float cg = tanh_fast(vc[f][r] + b_c);
            float cold = csrcF[o];
            float cy = sigm(fv) * cold + sigm(iv) * cg;
            float hy = sigm(ov) * (tanh_fast(cy) + vr[f][r]);
            cdstF[o] = cy;
            cdstB[o] = (__bf16)cy;
            hdstB[o] = (__bf16)hy;
            if (t == TT - 1) hfin[(size_t)j * SLOT + o] = hy;
            if (j == LL - 1) dout[(size_t)t * SLOT + o] = hy;
        }
    }
}

extern "C" void kernel_launch(void* const* d_in, const int* in_sizes, int n_in,
                              void* d_out, int out_size, void* d_ws, size_t ws_size,
                              hipStream_t stream) {
    const float* x      = (const float*)d_in[0];
    const float* hidden = (const float*)d_in[1];
    const float* Wii    = (const float*)d_in[2];
    const float* Wic    = (const float*)d_in[3];
    const float* Wih    = (const float*)d_in[4];
    const float* bii    = (const float*)d_in[5];
    const float* bic    = (const float*)d_in[6];
    const float* bih    = (const float*)d_in[7];
    const float* Whh    = (const float*)d_in[8];
    const float* bhh    = (const float*)d_in[9];
    const float* Wir    = (const float*)d_in[10];
    float* out = (float*)d_out;

    // ws layout (bytes):
    //   Wg     @ 0          75,497,472
    //   Whh_b  @ 75497472    8,388,608
    //   Wir_b  @ 83886080    8,388,608
    //   cbufF  @ 92274688    4,194,304
    //   bsum   @ 96468992       65,536
    //   hb     @ 96534528    2,097,152
    //   cb     @ 98631680    2,097,152
    //   hfin   @ 100728832   2,097,152
    char* ws = (char*)d_ws;
    __bf16* Wg    = (__bf16*)(ws);
    __bf16* Whh_b = (__bf16*)(ws + 75497472);
    __bf16* Wir_b = (__bf16*)(ws + 83886080);
    float*  cbufF = (float*)(ws + 92274688);
    float*  bsum  = (float*)(ws + 96468992);
    __bf16* hb    = (__bf16*)(ws + 96534528);
    __bf16* cb    = (__bf16*)(ws + 98631680);
    float*  hfin  = (float*)(ws + 100728832);

    k_conv_gates<<<4096, 256, 0, stream>>>(Wii, Wic, Wih, Wg);
    k_conv_plain<<<2048, 256, 0, stream>>>(Whh, Whh_b, (unsigned)(LL * HH * HH));
    k_conv_plain<<<2048, 256, 0, stream>>>(Wir, Wir_b, (unsigned)(LL * HH * IN_D));
    k_bias<<<64, 256, 0, stream>>>(bii, bic, bih, bhh, bsum);
    k_init<<<1024, 256, 0, stream>>>(hidden, cbufF, hb, cb);

    dim3 grid(64, LL), block(256);
    for (int s = 0; s < NSUPER; ++s)
        k_super<<<grid, block, 0, stream>>>(x, Wg, Whh_b, Wir_b, bsum,
                                            cbufF, hb, cb, hfin, out, s);

    k_final<<<1024, 256, 0, stream>>>(hfin, cbufF, out + (size_t)TT * SLOT);
}